// Round 9
// baseline (1605.092 us; speedup 1.0000x reference)
//
#include <hip/hip_runtime.h>
#include <math.h>

#define B_ 8192
#define DIN_ 2048
#define H_ 1024
#define V_ 6
#define T_ 6

typedef short bf16x8 __attribute__((ext_vector_type(8)));
typedef float f32x4 __attribute__((ext_vector_type(4)));

__device__ __forceinline__ unsigned short f32_bf16(float f) {
    unsigned u = __float_as_uint(f);
    u += 0x7FFFu + ((u >> 16) & 1u);
    return (unsigned short)(u >> 16);
}
__device__ __forceinline__ float bf16_f32(unsigned short h) {
    return __uint_as_float(((unsigned)h) << 16);
}
// fast transcendentals for epilogues: |err| ~1e-6, far below the stable
// 3.9e-3 absmax of the split-bf16 pipeline (verified rounds 4-8: absmax
// unchanged at 0.00390625 with these enabled).
__device__ __forceinline__ float sigm_fast(float v) {
    return 1.0f / (1.0f + __expf(-v));
}
__device__ __forceinline__ float tanh_fast(float v) {
    return 1.0f - 2.0f / (1.0f + __expf(2.0f * v));
}

#define GLL16(g, l) __builtin_amdgcn_global_load_lds(                       \
        (const __attribute__((address_space(1))) void*)(g),                  \
        (__attribute__((address_space(3))) void*)(l), 16, 0, 0)

// ---------------------------------------------------------------------------
// conv_w: full 2048x1024 f32 W -> fragment planes, NKB=256 (W_enc only).
// plane addr (halves) = ((n>>4)*NKB + kb)*128 + (n&15)*8 + k8
// ---------------------------------------------------------------------------
__global__ __launch_bounds__(256) void conv_w(const float* __restrict__ W,
        unsigned short* __restrict__ hi, unsigned short* __restrict__ lo)
{
    const int t = blockIdx.x * 256 + threadIdx.x;   // 256K
    const int n = t & 1023;
    const int kb = t >> 10;                          // 0..255
    unsigned hq[4], lq[4];
#pragma unroll
    for (int p = 0; p < 4; ++p) {
        const float v0 = W[(size_t)(kb * 8 + 2 * p) * 1024 + n];
        const float v1 = W[(size_t)(kb * 8 + 2 * p + 1) * 1024 + n];
        const unsigned short h0 = f32_bf16(v0), h1 = f32_bf16(v1);
        const unsigned short l0 = f32_bf16(v0 - bf16_f32(h0));
        const unsigned short l1 = f32_bf16(v1 - bf16_f32(h1));
        hq[p] = (unsigned)h0 | ((unsigned)h1 << 16);
        lq[p] = (unsigned)l0 | ((unsigned)l1 << 16);
    }
    const size_t c = ((size_t)(n >> 4) * 256 + kb) * 128 + (size_t)(n & 15) * 8;
    *(uint4*)(hi + c) = make_uint4(hq[0], hq[1], hq[2], hq[3]);
    *(uint4*)(lo + c) = make_uint4(lq[0], lq[1], lq[2], lq[3]);
}

// ---------------------------------------------------------------------------
// conv_wb: BOTTOM half (rows 1024..2047) of 2048x1024 W -> planes, NKB=128.
// ---------------------------------------------------------------------------
__global__ __launch_bounds__(256) void conv_wb(const float* __restrict__ W,
        unsigned short* __restrict__ hi, unsigned short* __restrict__ lo)
{
    const int t = blockIdx.x * 256 + threadIdx.x;   // 128K
    const int n = t & 1023;
    const int kb = t >> 10;                          // 0..127
    unsigned hq[4], lq[4];
#pragma unroll
    for (int p = 0; p < 4; ++p) {
        const float v0 = W[(size_t)(1024 + kb * 8 + 2 * p) * 1024 + n];
        const float v1 = W[(size_t)(1024 + kb * 8 + 2 * p + 1) * 1024 + n];
        const unsigned short h0 = f32_bf16(v0), h1 = f32_bf16(v1);
        const unsigned short l0 = f32_bf16(v0 - bf16_f32(h0));
        const unsigned short l1 = f32_bf16(v1 - bf16_f32(h1));
        hq[p] = (unsigned)h0 | ((unsigned)h1 << 16);
        lq[p] = (unsigned)l0 | ((unsigned)l1 << 16);
    }
    const size_t c = ((size_t)(n >> 4) * 128 + kb) * 128 + (size_t)(n & 15) * 8;
    *(uint4*)(hi + c) = make_uint4(hq[0], hq[1], hq[2], hq[3]);
    *(uint4*)(lo + c) = make_uint4(lq[0], lq[1], lq[2], lq[3]);
}

// ---------------------------------------------------------------------------
// conv_x: x (8192x2048 f32) -> A planes, NKB=256.
// ---------------------------------------------------------------------------
__global__ __launch_bounds__(256) void conv_x(const float* __restrict__ X,
        unsigned short* __restrict__ hi, unsigned short* __restrict__ lo)
{
    const size_t t = (size_t)blockIdx.x * 256 + threadIdx.x;  // 8192*256
    const int kb = (int)(t & 255);
    const int m = (int)(t >> 8);
    const float4 f0 = *(const float4*)(X + (size_t)m * 2048 + kb * 8);
    const float4 f1 = *(const float4*)(X + (size_t)m * 2048 + kb * 8 + 4);
    const float v[8] = {f0.x, f0.y, f0.z, f0.w, f1.x, f1.y, f1.z, f1.w};
    unsigned hq[4], lq[4];
#pragma unroll
    for (int p = 0; p < 4; ++p) {
        const unsigned short h0 = f32_bf16(v[2 * p]);
        const unsigned short h1 = f32_bf16(v[2 * p + 1]);
        const unsigned short l0 = f32_bf16(v[2 * p] - bf16_f32(h0));
        const unsigned short l1 = f32_bf16(v[2 * p + 1] - bf16_f32(h1));
        hq[p] = (unsigned)h0 | ((unsigned)h1 << 16);
        lq[p] = (unsigned)l0 | ((unsigned)l1 << 16);
    }
    const size_t c = ((size_t)(m >> 4) * 256 + kb) * 128 + (size_t)(m & 15) * 8;
    *(uint4*)(hi + c) = make_uint4(hq[0], hq[1], hq[2], hq[3]);
    *(uint4*)(lo + c) = make_uint4(lq[0], lq[1], lq[2], lq[3]);
}

// ---------------------------------------------------------------------------
// prep_tables: P_m[tok][n] = sum_k emb[tok][k] * W_m[k][n] + b_m[n]
// ---------------------------------------------------------------------------
__global__ __launch_bounds__(256) void prep_tables(
        const float* __restrict__ Wz, const float* __restrict__ Wr,
        const float* __restrict__ Wh,
        const float* __restrict__ bz, const float* __restrict__ br,
        const float* __restrict__ bh,
        const float* __restrict__ Wt, const float* __restrict__ bt,
        const float* __restrict__ se,
        float* __restrict__ Pz, float* __restrict__ Pr, float* __restrict__ Ph)
{
    __shared__ float emb[7][1024];
    const int tid = threadIdx.x;
    for (int i = tid; i < 7 * 1024; i += 256) {
        const int r = i >> 10, k = i & 1023;
        emb[r][k] = (r < 6) ? (Wt[(size_t)r * 1024 + k] + bt[k]) : se[k];
    }
    __syncthreads();
    const float* W = (blockIdx.y == 0) ? Wz : ((blockIdx.y == 1) ? Wr : Wh);
    const float* bb = (blockIdx.y == 0) ? bz : ((blockIdx.y == 1) ? br : bh);
    float* P = (blockIdx.y == 0) ? Pz : ((blockIdx.y == 1) ? Pr : Ph);
    const int n = blockIdx.x * 256 + tid;
    float acc[7] = {0.f, 0.f, 0.f, 0.f, 0.f, 0.f, 0.f};
    for (int k = 0; k < 1024; ++k) {
        const float wv = W[(size_t)k * 1024 + n];
#pragma unroll
        for (int r = 0; r < 7; ++r) acc[r] = fmaf(emb[r][k], wv, acc[r]);
    }
    const float bvv = bb[n];
#pragma unroll
    for (int r = 0; r < 7; ++r) P[(size_t)r * 1024 + n] = acc[r] + bvv;
}

// ---------------------------------------------------------------------------
// init_misc: tokidx = 6 (start), rc = 1, nt = 0.
// ---------------------------------------------------------------------------
__global__ __launch_bounds__(256) void init_misc(
        int* __restrict__ tokidx, float* __restrict__ rc, float* __restrict__ nt)
{
    const int t = blockIdx.x * 256 + threadIdx.x;   // 8192
    tokidx[t] = 6;
    rc[t] = 1.0f;
    nt[t] = 0.0f;
}

// ---------------------------------------------------------------------------
// gemm_bt: ROUND-8 verified structure (128x128 tile, BK=32, 8 waves/512 thr,
// 32x64 per-wave sub-tile, LDS double-buffer 2x32KB, one barrier/step,
// 2 resident blocks/CU) with ROUND-9 issue-slot trim:
//  - K-loop unrolled x2 with STATIC buffer bases L0/L1 (compile-time LDS
//    addressing -> ds_read offsets fold to immediates; the runtime
//    ((s&1)<<14) base previously cost a VALU add on every LDS access)
//  - global staging pointers advance incrementally (+512 halves/step)
//    instead of re-deriving base + s*512 with 64-bit mads each step.
// Same data movement, same barrier rhythm; final pre-epilogue barrier
// dropped (epilogue touches no LDS). Evidence: r8 counters show VALUBusy
// 29.8% ~ MFMA issue share; addressing is the remaining cuttable slice.
// ---------------------------------------------------------------------------
__global__ __launch_bounds__(512, 3)
void gemm_bt(
    const unsigned short* __restrict__ A_hi, const unsigned short* __restrict__ A_lo,
    const unsigned short* __restrict__ B0_hi, const unsigned short* __restrict__ B0_lo,
    const unsigned short* __restrict__ B1_hi, const unsigned short* __restrict__ B1_lo,
    const float* __restrict__ P0, const float* __restrict__ P1,
    const int* __restrict__ tokidx,
    const float* __restrict__ zbuf, float* __restrict__ hbuf,
    float* __restrict__ outf,
    unsigned short* __restrict__ ophi, unsigned short* __restrict__ oplo,
    int nkb, int mode)
{
    __shared__ unsigned short lds[32768];   // 64KB: 2 x (Ahi|Alo|Bhi|Blo)

    const int tid = threadIdx.x;
    const int lane = tid & 63;
    const int w = tid >> 6;                  // 0..7

    // ---- XCD-aware swizzle (bijective relabel of the NX x 64 grid) ----
    const int NX = gridDim.x;
    const int lin = blockIdx.y * NX + blockIdx.x;
    const int xcd = lin & 7;
    const int idx = lin >> 3;                // 0 .. NX*8-1
    int bx = idx % NX;                       // fastest: co-resident share by
    const int by = xcd * 8 + idx / NX;       // contiguous by-band per XCD

    const unsigned short* Bhi = B0_hi;
    const unsigned short* Blo = B0_lo;
    const float* Pm = P0;
    int isR = 0;
    if (mode == 1 && bx >= 8) { bx -= 8; Bhi = B1_hi; Blo = B1_lo; Pm = P1; isR = 1; }

    const int m0 = by * 128;
    const int n0 = bx * 128;
    const int gma = by * 8 + w;              // this wave's A group (of 8)
    const int gnb = bx * 8 + w;              // this wave's B group (of 8)

    // per-wave LDS staging offsets within a buffer (halves)
    const int dA = w * 512 + lane * 8;
    const int dB = 8192 + w * 512 + lane * 8;

    f32x4 acc[2][4];
#pragma unroll
    for (int i = 0; i < 2; ++i)
#pragma unroll
        for (int j = 0; j < 4; ++j) acc[i][j] = (f32x4){0.f, 0.f, 0.f, 0.f};

    const int wr = w >> 1, wc = w & 1;       // wave sub-tile: rows wr*32, cols wc*64
    const int fq = lane >> 4;
    const int fm = lane & 15;
    const int nsteps = nkb >> 2;             // 32 or 64 (always even, >= 4)

    // incremental global staging pointers (halves); +512 per K-step
    const unsigned short* pAh = A_hi + (size_t)gma * nkb * 128 + lane * 8;
    const unsigned short* pAl = A_lo + (size_t)gma * nkb * 128 + lane * 8;
    const unsigned short* pBh = Bhi + (size_t)gnb * nkb * 128 + lane * 8;
    const unsigned short* pBl = Blo + (size_t)gnb * nkb * 128 + lane * 8;

    unsigned short* const L0 = lds;          // even steps
    unsigned short* const L1 = lds + 16384;  // odd steps

#define STAGE_TO(dst_) do {                                                    \
    GLL16(pAh, (dst_) + dA); GLL16(pAl, (dst_) + 4096 + dA);                   \
    GLL16(pBh, (dst_) + dB); GLL16(pBl, (dst_) + 4096 + dB);                   \
    pAh += 512; pAl += 512; pBh += 512; pBl += 512;                            \
} while (0)

#define COMPUTE_FROM(cb_) do {                                                 \
    bf16x8 ah[2], al[2];                                                       \
    _Pragma("unroll")                                                          \
    for (int i = 0; i < 2; ++i) {                                              \
        const int ra = (wr * 2 + i) * 512 + fq * 128 + fm * 8;                 \
        ah[i] = *(const bf16x8*)((cb_) + ra);                                  \
        al[i] = *(const bf16x8*)((cb_) + 4096 + ra);                           \
    }                                                                          \
    _Pragma("unroll")                                                          \
    for (int j = 0; j < 4; ++j) {                                              \
        const int rb = 8192 + (wc * 4 + j) * 512 + fq * 128 + fm * 8;          \
        const bf16x8 bh = *(const bf16x8*)((cb_) + rb);                        \
        const bf16x8 bl = *(const bf16x8*)((cb_) + 4096 + rb);                 \
        _Pragma("unroll")                                                      \
        for (int i = 0; i < 2; ++i) {                                          \
            acc[i][j] = __builtin_amdgcn_mfma_f32_16x16x32_bf16(ah[i], bh, acc[i][j], 0, 0, 0); \
            acc[i][j] = __builtin_amdgcn_mfma_f32_16x16x32_bf16(ah[i], bl, acc[i][j], 0, 0, 0); \
            acc[i][j] = __builtin_amdgcn_mfma_f32_16x16x32_bf16(al[i], bh, acc[i][j], 0, 0, 0); \
        }                                                                      \
    }                                                                          \
} while (0)

    // prologue: stage step 0 into L0
    STAGE_TO(L0);
    __syncthreads();                          // compiler drains vmcnt before barrier

#pragma unroll 1
    for (int s = 0; s < nsteps - 2; s += 2) {
        STAGE_TO(L1);                         // step s+1
        COMPUTE_FROM(L0);                     // step s
        __syncthreads();
        STAGE_TO(L0);                         // step s+2
        COMPUTE_FROM(L1);                     // step s+1
        __syncthreads();
    }
    // tail: steps nsteps-2 (in L0) and nsteps-1 (staged now into L1)
    STAGE_TO(L1);
    COMPUTE_FROM(L0);
    __syncthreads();
    COMPUTE_FROM(L1);

#undef STAGE_TO
#undef COMPUTE_FROM

    // ---- epilogue ----
#pragma unroll
    for (int i = 0; i < 2; ++i) {
        int toks[4];
#pragma unroll
        for (int r = 0; r < 4; ++r) {
            const int row = m0 + wr * 32 + i * 16 + fq * 4 + r;
            toks[r] = tokidx ? tokidx[row] : 0;
        }
#pragma unroll
        for (int j = 0; j < 4; ++j) {
            const int col = n0 + wc * 64 + j * 16 + fm;
#pragma unroll
            for (int r = 0; r < 4; ++r) {
                const int row = m0 + wr * 32 + i * 16 + fq * 4 + r;
                const float v = acc[i][j][r] + Pm[(size_t)toks[r] * 1024 + col];
                const size_t off = (size_t)row * 1024 + col;
                const size_t pc = ((size_t)(row >> 4) * 128 + (col >> 3)) * 128
                                  + (size_t)(row & 15) * 8 + (col & 7);
                if (mode == 0) {
                    hbuf[off] = v;
                    const unsigned short hv = f32_bf16(v);
                    ophi[pc] = hv;
                    oplo[pc] = f32_bf16(v - bf16_f32(hv));
                } else if (mode == 1) {
                    const float sg = sigm_fast(v);
                    if (!isR) {
                        outf[off] = sg;
                    } else {
                        const float rh = sg * hbuf[off];
                        const unsigned short hv = f32_bf16(rh);
                        ophi[pc] = hv;
                        oplo[pc] = f32_bf16(rh - bf16_f32(hv));
                    }
                } else {
                    const float tv = tanh_fast(v);
                    const float zv = zbuf[off];
                    const float hn = (1.0f - zv) * hbuf[off] + zv * tv;
                    hbuf[off] = hn;
                    const unsigned short hv = f32_bf16(hn);
                    ophi[pc] = hv;
                    oplo[pc] = f32_bf16(hn - bf16_f32(hv));
                }
            }
        }
    }
}

// ---------------------------------------------------------------------------
// step_tok: one wave per batch row.
// ---------------------------------------------------------------------------
__global__ __launch_bounds__(256)
void step_tok(const float* __restrict__ h,
              const float* __restrict__ W_out, const float* __restrict__ b_out,
              const float* __restrict__ u,
              float* __restrict__ rc, float* __restrict__ nt,
              int* __restrict__ tokidx,
              float* __restrict__ out_msg, float* __restrict__ out_logits,
              float* __restrict__ out_nt, int t)
{
    const int lane = threadIdx.x & 63;
    const int wv = threadIdx.x >> 6;
    const int b = blockIdx.x * 4 + wv;

    const float* hr = h + (size_t)b * H_;
    float s[6] = {0.f, 0.f, 0.f, 0.f, 0.f, 0.f};
#pragma unroll
    for (int i = 0; i < 4; ++i) {
        const int k0 = i * 256 + lane * 4;
        const float4 hv = *(const float4*)(hr + k0);
        const float he[4] = {hv.x, hv.y, hv.z, hv.w};
#pragma unroll
        for (int e = 0; e < 4; ++e) {
            const float* wp = W_out + (size_t)(k0 + e) * V_;
            const float xv = he[e];
#pragma unroll
            for (int v = 0; v < 6; ++v) s[v] = fmaf(xv, wp[v], s[v]);
        }
    }
#pragma unroll
    for (int m = 1; m < 64; m <<= 1) {
#pragma unroll
        for (int v = 0; v < 6; ++v) s[v] += __shfl_xor(s[v], m, 64);
    }

    float lg[6];
#pragma unroll
    for (int v = 0; v < 6; ++v) lg[v] = s[v] + b_out[v];

    const float* ub = u + (size_t)b * V_;
    const float eps = 1e-10f;
    float aa[6];
#pragma unroll
    for (int v = 0; v < 6; ++v) {
        const float g = -logf(-logf(ub[v] + eps) + eps);
        aa[v] = lg[v] + g;  // TAU = 1
    }
    int tok = 0;
    float best = aa[0];
#pragma unroll
    for (int v = 1; v < 6; ++v)
        if (aa[v] > best) { best = aa[v]; tok = v; }

    if (lane == 0) {
        const float rco = rc[b];
#pragma unroll
        for (int v = 0; v < 6; ++v) out_logits[(size_t)b * 6 + v] = lg[v];
#pragma unroll
        for (int v = 0; v < 6; ++v)
            out_msg[(size_t)b * 36 + t * 6 + v] = (v == tok) ? rco : 0.0f;
        const float ntn = nt[b] + rco;
        nt[b] = ntn;
        out_nt[b] = ntn;
        rc[b] = (tok == 5) ? 0.0f : rco;
        tokidx[b] = tok;
    }
}

// ---------------------------------------------------------------------------
extern "C" void kernel_launch(void* const* d_in, const int* in_sizes, int n_in,
                              void* d_out, int out_size, void* d_ws, size_t ws_size,
                              hipStream_t stream)
{
    (void)in_sizes; (void)n_in; (void)out_size; (void)ws_size;
    const float* x       = (const float*)d_in[0];
    const float* u_noise = (const float*)d_in[1];
    const float* W_enc   = (const float*)d_in[2];
    const float* b_enc   = (const float*)d_in[3];
    const float* start_e = (const float*)d_in[4];
    const float* W_tok   = (const float*)d_in[5];
    const float* b_tok   = (const float*)d_in[6];
    const float* Wz      = (const float*)d_in[7];
    const float* bz      = (const float*)d_in[8];
    const float* Wr      = (const float*)d_in[9];
    const float* br      = (const float*)d_in[10];
    const float* Wh      = (const float*)d_in[11];
    const float* bh      = (const float*)d_in[12];
    const float* W_out   = (const float*)d_in[13];
    const float* b_out   = (const float*)d_in[14];

    float* out = (float*)d_out;
    float* out_msg = out;                                   // (B, T*V)
    float* out_logits = out + (size_t)B_ * T_ * V_;         // (T, B, V)
    float* out_nt = out_logits + (size_t)T_ * B_ * V_;      // (B,)

    // ---- workspace layout (~148.1 MB) ----
    char* wsb = (char*)d_ws;
    const size_t MB = 1024 * 1024;
    unsigned short* wzb_hi = (unsigned short*)(wsb + 0 * MB);    // 2MB each
    unsigned short* wzb_lo = (unsigned short*)(wsb + 2 * MB);
    unsigned short* wrb_hi = (unsigned short*)(wsb + 4 * MB);
    unsigned short* wrb_lo = (unsigned short*)(wsb + 6 * MB);
    unsigned short* whb_hi = (unsigned short*)(wsb + 8 * MB);
    unsigned short* whb_lo = (unsigned short*)(wsb + 10 * MB);
    unsigned short* we_hi  = (unsigned short*)(wsb + 12 * MB);   // 4MB
    unsigned short* we_lo  = (unsigned short*)(wsb + 16 * MB);   // 4MB
    unsigned short* x_hi   = (unsigned short*)(wsb + 20 * MB);   // 32MB
    unsigned short* x_lo   = (unsigned short*)(wsb + 52 * MB);   // 32MB
    float*  zbuf  = (float*)(wsb + 20 * MB);                     // alias x_hi
    unsigned short* rh_hi  = (unsigned short*)(wsb + 52 * MB);   // alias x_lo
    unsigned short* rh_lo  = (unsigned short*)(wsb + 68 * MB);
    float*  hbuf  = (float*)(wsb + 84 * MB);                     // 32MB
    unsigned short* h_hi   = (unsigned short*)(wsb + 116 * MB);  // 16MB
    unsigned short* h_lo   = (unsigned short*)(wsb + 132 * MB);  // 16MB
    float* Pz = (float*)(wsb + 148 * MB);                        // 7x1024 each
    float* Pr = Pz + 7 * 1024;
    float* Ph = Pr + 7 * 1024;
    int* tokidx = (int*)(Ph + 7 * 1024);
    float* rcb = (float*)(tokidx + B_);
    float* ntb = rcb + B_;

    // ---- one-time conversions / tables ----
    conv_wb<<<512, 256, 0, stream>>>(Wz, wzb_hi, wzb_lo);
    conv_wb<<<512, 256, 0, stream>>>(Wr, wrb_hi, wrb_lo);
    conv_wb<<<512, 256, 0, stream>>>(Wh, whb_hi, whb_lo);
    conv_w<<<1024, 256, 0, stream>>>(W_enc, we_hi, we_lo);
    conv_x<<<8192, 256, 0, stream>>>(x, x_hi, x_lo);
    prep_tables<<<dim3(4, 3), 256, 0, stream>>>(Wz, Wr, Wh, bz, br, bh,
                                                W_tok, b_tok, start_e, Pz, Pr, Ph);
    init_misc<<<32, 256, 0, stream>>>(tokidx, rcb, ntb);

    // ---- encoder: h0 = x @ W_enc + b_enc (K=2048) ----
    gemm_bt<<<dim3(8, 64), 512, 0, stream>>>(
        x_hi, x_lo, we_hi, we_lo, nullptr, nullptr,
        b_enc, nullptr, nullptr,
        nullptr, hbuf, nullptr, h_hi, h_lo, 256, 0);

    for (int t = 0; t < T_; ++t) {
        // z = sigmoid(h@Wz_bot + Pz[tok]); rh = sigmoid(h@Wr_bot + Pr[tok]) * h
        gemm_bt<<<dim3(16, 64), 512, 0, stream>>>(
            h_hi, h_lo, wzb_hi, wzb_lo, wrb_hi, wrb_lo,
            Pz, Pr, tokidx,
            nullptr, hbuf, zbuf, rh_hi, rh_lo, 128, 1);
        // h = (1-z)h + z*tanh(rh@Wh_bot + Ph[tok])
        gemm_bt<<<dim3(8, 64), 512, 0, stream>>>(
            rh_hi, rh_lo, whb_hi, whb_lo, nullptr, nullptr,
            Ph, nullptr, tokidx,
            zbuf, hbuf, nullptr, h_hi, h_lo, 128, 2);
        // logits / gumbel argmax / outputs / tokidx
        step_tok<<<B_ / 4, 256, 0, stream>>>(
            hbuf, W_out, b_out, u_noise + (size_t)t * B_ * V_,
            rcb, ntb, tokidx, out_msg,
            out_logits + (size_t)t * B_ * V_, out_nt, t);
    }
}

// Round 10
// 1581.945 us; speedup vs baseline: 1.0146x; 1.0146x over previous
//
#include <hip/hip_runtime.h>
#include <math.h>

#define B_ 8192
#define DIN_ 2048
#define H_ 1024
#define V_ 6
#define T_ 6

typedef short bf16x8 __attribute__((ext_vector_type(8)));
typedef float f32x4 __attribute__((ext_vector_type(4)));

__device__ __forceinline__ unsigned short f32_bf16(float f) {
    unsigned u = __float_as_uint(f);
    u += 0x7FFFu + ((u >> 16) & 1u);
    return (unsigned short)(u >> 16);
}
__device__ __forceinline__ float bf16_f32(unsigned short h) {
    return __uint_as_float(((unsigned)h) << 16);
}
// fast transcendentals for epilogues: |err| ~1e-6, far below the stable
// 3.9e-3 absmax of the split-bf16 pipeline (verified rounds 4-9: absmax
// unchanged at 0.00390625 with these enabled).
__device__ __forceinline__ float sigm_fast(float v) {
    return 1.0f / (1.0f + __expf(-v));
}
__device__ __forceinline__ float tanh_fast(float v) {
    return 1.0f - 2.0f / (1.0f + __expf(2.0f * v));
}

#define GLL16(g, l) __builtin_amdgcn_global_load_lds(                       \
        (const __attribute__((address_space(1))) void*)(g),                  \
        (__attribute__((address_space(3))) void*)(l), 16, 0, 0)

// ---------------------------------------------------------------------------
// conv_w: full 2048x1024 f32 W -> fragment planes, NKB=256 (W_enc only).
// plane addr (halves) = ((n>>4)*NKB + kb)*128 + (n&15)*8 + k8
// ---------------------------------------------------------------------------
__global__ __launch_bounds__(256) void conv_w(const float* __restrict__ W,
        unsigned short* __restrict__ hi, unsigned short* __restrict__ lo)
{
    const int t = blockIdx.x * 256 + threadIdx.x;   // 256K
    const int n = t & 1023;
    const int kb = t >> 10;                          // 0..255
    unsigned hq[4], lq[4];
#pragma unroll
    for (int p = 0; p < 4; ++p) {
        const float v0 = W[(size_t)(kb * 8 + 2 * p) * 1024 + n];
        const float v1 = W[(size_t)(kb * 8 + 2 * p + 1) * 1024 + n];
        const unsigned short h0 = f32_bf16(v0), h1 = f32_bf16(v1);
        const unsigned short l0 = f32_bf16(v0 - bf16_f32(h0));
        const unsigned short l1 = f32_bf16(v1 - bf16_f32(h1));
        hq[p] = (unsigned)h0 | ((unsigned)h1 << 16);
        lq[p] = (unsigned)l0 | ((unsigned)l1 << 16);
    }
    const size_t c = ((size_t)(n >> 4) * 256 + kb) * 128 + (size_t)(n & 15) * 8;
    *(uint4*)(hi + c) = make_uint4(hq[0], hq[1], hq[2], hq[3]);
    *(uint4*)(lo + c) = make_uint4(lq[0], lq[1], lq[2], lq[3]);
}

// ---------------------------------------------------------------------------
// conv_wb: BOTTOM half (rows 1024..2047) of 2048x1024 W -> planes, NKB=128.
// ---------------------------------------------------------------------------
__global__ __launch_bounds__(256) void conv_wb(const float* __restrict__ W,
        unsigned short* __restrict__ hi, unsigned short* __restrict__ lo)
{
    const int t = blockIdx.x * 256 + threadIdx.x;   // 128K
    const int n = t & 1023;
    const int kb = t >> 10;                          // 0..127
    unsigned hq[4], lq[4];
#pragma unroll
    for (int p = 0; p < 4; ++p) {
        const float v0 = W[(size_t)(1024 + kb * 8 + 2 * p) * 1024 + n];
        const float v1 = W[(size_t)(1024 + kb * 8 + 2 * p + 1) * 1024 + n];
        const unsigned short h0 = f32_bf16(v0), h1 = f32_bf16(v1);
        const unsigned short l0 = f32_bf16(v0 - bf16_f32(h0));
        const unsigned short l1 = f32_bf16(v1 - bf16_f32(h1));
        hq[p] = (unsigned)h0 | ((unsigned)h1 << 16);
        lq[p] = (unsigned)l0 | ((unsigned)l1 << 16);
    }
    const size_t c = ((size_t)(n >> 4) * 128 + kb) * 128 + (size_t)(n & 15) * 8;
    *(uint4*)(hi + c) = make_uint4(hq[0], hq[1], hq[2], hq[3]);
    *(uint4*)(lo + c) = make_uint4(lq[0], lq[1], lq[2], lq[3]);
}

// ---------------------------------------------------------------------------
// conv_x: x (8192x2048 f32) -> A planes, NKB=256.
// ---------------------------------------------------------------------------
__global__ __launch_bounds__(256) void conv_x(const float* __restrict__ X,
        unsigned short* __restrict__ hi, unsigned short* __restrict__ lo)
{
    const size_t t = (size_t)blockIdx.x * 256 + threadIdx.x;  // 8192*256
    const int kb = (int)(t & 255);
    const int m = (int)(t >> 8);
    const float4 f0 = *(const float4*)(X + (size_t)m * 2048 + kb * 8);
    const float4 f1 = *(const float4*)(X + (size_t)m * 2048 + kb * 8 + 4);
    const float v[8] = {f0.x, f0.y, f0.z, f0.w, f1.x, f1.y, f1.z, f1.w};
    unsigned hq[4], lq[4];
#pragma unroll
    for (int p = 0; p < 4; ++p) {
        const unsigned short h0 = f32_bf16(v[2 * p]);
        const unsigned short h1 = f32_bf16(v[2 * p + 1]);
        const unsigned short l0 = f32_bf16(v[2 * p] - bf16_f32(h0));
        const unsigned short l1 = f32_bf16(v[2 * p + 1] - bf16_f32(h1));
        hq[p] = (unsigned)h0 | ((unsigned)h1 << 16);
        lq[p] = (unsigned)l0 | ((unsigned)l1 << 16);
    }
    const size_t c = ((size_t)(m >> 4) * 256 + kb) * 128 + (size_t)(m & 15) * 8;
    *(uint4*)(hi + c) = make_uint4(hq[0], hq[1], hq[2], hq[3]);
    *(uint4*)(lo + c) = make_uint4(lq[0], lq[1], lq[2], lq[3]);
}

// ---------------------------------------------------------------------------
// prep_tables: P_m[tok][n] = sum_k emb[tok][k] * W_m[k][n] + b_m[n]
// ---------------------------------------------------------------------------
__global__ __launch_bounds__(256) void prep_tables(
        const float* __restrict__ Wz, const float* __restrict__ Wr,
        const float* __restrict__ Wh,
        const float* __restrict__ bz, const float* __restrict__ br,
        const float* __restrict__ bh,
        const float* __restrict__ Wt, const float* __restrict__ bt,
        const float* __restrict__ se,
        float* __restrict__ Pz, float* __restrict__ Pr, float* __restrict__ Ph)
{
    __shared__ float emb[7][1024];
    const int tid = threadIdx.x;
    for (int i = tid; i < 7 * 1024; i += 256) {
        const int r = i >> 10, k = i & 1023;
        emb[r][k] = (r < 6) ? (Wt[(size_t)r * 1024 + k] + bt[k]) : se[k];
    }
    __syncthreads();
    const float* W = (blockIdx.y == 0) ? Wz : ((blockIdx.y == 1) ? Wr : Wh);
    const float* bb = (blockIdx.y == 0) ? bz : ((blockIdx.y == 1) ? br : bh);
    float* P = (blockIdx.y == 0) ? Pz : ((blockIdx.y == 1) ? Pr : Ph);
    const int n = blockIdx.x * 256 + tid;
    float acc[7] = {0.f, 0.f, 0.f, 0.f, 0.f, 0.f, 0.f};
    for (int k = 0; k < 1024; ++k) {
        const float wv = W[(size_t)k * 1024 + n];
#pragma unroll
        for (int r = 0; r < 7; ++r) acc[r] = fmaf(emb[r][k], wv, acc[r]);
    }
    const float bvv = bb[n];
#pragma unroll
    for (int r = 0; r < 7; ++r) P[(size_t)r * 1024 + n] = acc[r] + bvv;
}

// ---------------------------------------------------------------------------
// init_misc: tokidx = 6 (start), rc = 1, nt = 0.
// ---------------------------------------------------------------------------
__global__ __launch_bounds__(256) void init_misc(
        int* __restrict__ tokidx, float* __restrict__ rc, float* __restrict__ nt)
{
    const int t = blockIdx.x * 256 + threadIdx.x;   // 8192
    tokidx[t] = 6;
    rc[t] = 1.0f;
    nt[t] = 0.0f;
}

// ---------------------------------------------------------------------------
// gemm_bt: ROUND-8 BEST (total 1589us; z/r 120.0us, MfmaUtil 38.6) — restored
// verbatim after round-9's issue-slot trim regressed (VALUBusy fell 29.8->23.4
// as predicted but dur rose: VALU slots co-issue under the LDS/MFMA shadow and
// were never binding; the x2 static unroll de-synchronized co-resident blocks'
// L2 sharing, FETCH +17%).
// Structure: 128x128 tile, BK=32, 8 waves/512 thr, 32x64 per-wave sub-tile
// (acc[2][4]=32 AGPR), LDS double-buffer 2x32KB, ONE barrier per K-step:
//   iter s: STAGE(buf^1, s+1); COMPUTE(buf); barrier
// 2 resident blocks/CU (64KB LDS, 52 arch + 32 acc regs -> 16-wave class);
// cross-block overlap (m114) covers the stage/drain latency — every
// alternative that lost co-residency (r1,r2,r3,r6) or latency hiding (r7)
// regressed 9-34%.
// ---------------------------------------------------------------------------
__global__ __launch_bounds__(512, 3)
void gemm_bt(
    const unsigned short* __restrict__ A_hi, const unsigned short* __restrict__ A_lo,
    const unsigned short* __restrict__ B0_hi, const unsigned short* __restrict__ B0_lo,
    const unsigned short* __restrict__ B1_hi, const unsigned short* __restrict__ B1_lo,
    const float* __restrict__ P0, const float* __restrict__ P1,
    const int* __restrict__ tokidx,
    const float* __restrict__ zbuf, float* __restrict__ hbuf,
    float* __restrict__ outf,
    unsigned short* __restrict__ ophi, unsigned short* __restrict__ oplo,
    int nkb, int mode)
{
    __shared__ unsigned short lds[32768];   // 64KB: 2 x (Ahi|Alo|Bhi|Blo)

    const int tid = threadIdx.x;
    const int lane = tid & 63;
    const int w = tid >> 6;                  // 0..7

    // ---- XCD-aware swizzle (bijective relabel of the NX x 64 grid) ----
    const int NX = gridDim.x;
    const int lin = blockIdx.y * NX + blockIdx.x;
    const int xcd = lin & 7;
    const int idx = lin >> 3;                // 0 .. NX*8-1
    int bx = idx % NX;                       // fastest: co-resident share by
    const int by = xcd * 8 + idx / NX;       // contiguous by-band per XCD

    const unsigned short* Bhi = B0_hi;
    const unsigned short* Blo = B0_lo;
    const float* Pm = P0;
    int isR = 0;
    if (mode == 1 && bx >= 8) { bx -= 8; Bhi = B1_hi; Blo = B1_lo; Pm = P1; isR = 1; }

    const int m0 = by * 128;
    const int n0 = bx * 128;
    const int gma = by * 8 + w;              // this wave's A group (of 8)
    const int gnb = bx * 8 + w;              // this wave's B group (of 8)

    // per-wave LDS staging offsets within a buffer (halves)
    const int dA = w * 512 + lane * 8;
    const int dB = 8192 + w * 512 + lane * 8;

    f32x4 acc[2][4];
#pragma unroll
    for (int i = 0; i < 2; ++i)
#pragma unroll
        for (int j = 0; j < 4; ++j) acc[i][j] = (f32x4){0.f, 0.f, 0.f, 0.f};

    const int wr = w >> 1, wc = w & 1;       // wave sub-tile: rows wr*32, cols wc*64
    const int fq = lane >> 4;
    const int fm = lane & 15;
    const int nsteps = nkb >> 2;

    // wave-invariant global bases (halves); step stride = 4*128 = 512
    const size_t abase = (size_t)gma * nkb * 128 + lane * 8;
    const size_t bbase = (size_t)gnb * nkb * 128 + lane * 8;

    // ---- prologue: stage step 0 into buffer 0 ----
    {
        GLL16(A_hi + abase, lds + dA);
        GLL16(A_lo + abase, lds + 4096 + dA);
        GLL16(Bhi + bbase, lds + dB);
        GLL16(Blo + bbase, lds + 4096 + dB);
    }
    __syncthreads();                          // compiler drains vmcnt before barrier

#pragma unroll 1
    for (int s = 0; s < nsteps; ++s) {
        // phase 1: stage step s+1 into the other buffer (no wait)
        if (s + 1 < nsteps) {
            unsigned short* nb = lds + (((s + 1) & 1) << 14);
            const size_t oa = abase + (size_t)(s + 1) * 512;
            const size_t ob = bbase + (size_t)(s + 1) * 512;
            GLL16(A_hi + oa, nb + dA);
            GLL16(A_lo + oa, nb + 4096 + dA);
            GLL16(Bhi + ob, nb + dB);
            GLL16(Blo + ob, nb + 4096 + dB);
        }
        // phase 2: compute on current buffer
        const unsigned short* cb = lds + ((s & 1) << 14);
        bf16x8 ah[2], al[2];
#pragma unroll
        for (int i = 0; i < 2; ++i) {
            const int ra = (wr * 2 + i) * 512 + fq * 128 + fm * 8;
            ah[i] = *(const bf16x8*)(cb + ra);
            al[i] = *(const bf16x8*)(cb + 4096 + ra);
        }
#pragma unroll
        for (int j = 0; j < 4; ++j) {
            const int rb = 8192 + (wc * 4 + j) * 512 + fq * 128 + fm * 8;
            const bf16x8 bh = *(const bf16x8*)(cb + rb);
            const bf16x8 bl = *(const bf16x8*)(cb + 4096 + rb);
#pragma unroll
            for (int i = 0; i < 2; ++i) {
                acc[i][j] = __builtin_amdgcn_mfma_f32_16x16x32_bf16(ah[i], bh, acc[i][j], 0, 0, 0);
                acc[i][j] = __builtin_amdgcn_mfma_f32_16x16x32_bf16(ah[i], bl, acc[i][j], 0, 0, 0);
                acc[i][j] = __builtin_amdgcn_mfma_f32_16x16x32_bf16(al[i], bh, acc[i][j], 0, 0, 0);
            }
        }
        // one barrier per step: drains stage s+1 (vmcnt0 before s_barrier) and
        // guarantees all waves finished reading buffer s&1 before overwrite.
        __syncthreads();
    }

    // ---- epilogue ----
#pragma unroll
    for (int i = 0; i < 2; ++i) {
        int toks[4];
#pragma unroll
        for (int r = 0; r < 4; ++r) {
            const int row = m0 + wr * 32 + i * 16 + fq * 4 + r;
            toks[r] = tokidx ? tokidx[row] : 0;
        }
#pragma unroll
        for (int j = 0; j < 4; ++j) {
            const int col = n0 + wc * 64 + j * 16 + fm;
#pragma unroll
            for (int r = 0; r < 4; ++r) {
                const int row = m0 + wr * 32 + i * 16 + fq * 4 + r;
                const float v = acc[i][j][r] + Pm[(size_t)toks[r] * 1024 + col];
                const size_t off = (size_t)row * 1024 + col;
                const size_t pc = ((size_t)(row >> 4) * 128 + (col >> 3)) * 128
                                  + (size_t)(row & 15) * 8 + (col & 7);
                if (mode == 0) {
                    hbuf[off] = v;
                    const unsigned short hv = f32_bf16(v);
                    ophi[pc] = hv;
                    oplo[pc] = f32_bf16(v - bf16_f32(hv));
                } else if (mode == 1) {
                    const float sg = sigm_fast(v);
                    if (!isR) {
                        outf[off] = sg;
                    } else {
                        const float rh = sg * hbuf[off];
                        const unsigned short hv = f32_bf16(rh);
                        ophi[pc] = hv;
                        oplo[pc] = f32_bf16(rh - bf16_f32(hv));
                    }
                } else {
                    const float tv = tanh_fast(v);
                    const float zv = zbuf[off];
                    const float hn = (1.0f - zv) * hbuf[off] + zv * tv;
                    hbuf[off] = hn;
                    const unsigned short hv = f32_bf16(hn);
                    ophi[pc] = hv;
                    oplo[pc] = f32_bf16(hn - bf16_f32(hv));
                }
            }
        }
    }
}

// ---------------------------------------------------------------------------
// step_tok: one wave per batch row.
// ---------------------------------------------------------------------------
__global__ __launch_bounds__(256)
void step_tok(const float* __restrict__ h,
              const float* __restrict__ W_out, const float* __restrict__ b_out,
              const float* __restrict__ u,
              float* __restrict__ rc, float* __restrict__ nt,
              int* __restrict__ tokidx,
              float* __restrict__ out_msg, float* __restrict__ out_logits,
              float* __restrict__ out_nt, int t)
{
    const int lane = threadIdx.x & 63;
    const int wv = threadIdx.x >> 6;
    const int b = blockIdx.x * 4 + wv;

    const float* hr = h + (size_t)b * H_;
    float s[6] = {0.f, 0.f, 0.f, 0.f, 0.f, 0.f};
#pragma unroll
    for (int i = 0; i < 4; ++i) {
        const int k0 = i * 256 + lane * 4;
        const float4 hv = *(const float4*)(hr + k0);
        const float he[4] = {hv.x, hv.y, hv.z, hv.w};
#pragma unroll
        for (int e = 0; e < 4; ++e) {
            const float* wp = W_out + (size_t)(k0 + e) * V_;
            const float xv = he[e];
#pragma unroll
            for (int v = 0; v < 6; ++v) s[v] = fmaf(xv, wp[v], s[v]);
        }
    }
#pragma unroll
    for (int m = 1; m < 64; m <<= 1) {
#pragma unroll
        for (int v = 0; v < 6; ++v) s[v] += __shfl_xor(s[v], m, 64);
    }

    float lg[6];
#pragma unroll
    for (int v = 0; v < 6; ++v) lg[v] = s[v] + b_out[v];

    const float* ub = u + (size_t)b * V_;
    const float eps = 1e-10f;
    float aa[6];
#pragma unroll
    for (int v = 0; v < 6; ++v) {
        const float g = -logf(-logf(ub[v] + eps) + eps);
        aa[v] = lg[v] + g;  // TAU = 1
    }
    int tok = 0;
    float best = aa[0];
#pragma unroll
    for (int v = 1; v < 6; ++v)
        if (aa[v] > best) { best = aa[v]; tok = v; }

    if (lane == 0) {
        const float rco = rc[b];
#pragma unroll
        for (int v = 0; v < 6; ++v) out_logits[(size_t)b * 6 + v] = lg[v];
#pragma unroll
        for (int v = 0; v < 6; ++v)
            out_msg[(size_t)b * 36 + t * 6 + v] = (v == tok) ? rco : 0.0f;
        const float ntn = nt[b] + rco;
        nt[b] = ntn;
        out_nt[b] = ntn;
        rc[b] = (tok == 5) ? 0.0f : rco;
        tokidx[b] = tok;
    }
}

// ---------------------------------------------------------------------------
extern "C" void kernel_launch(void* const* d_in, const int* in_sizes, int n_in,
                              void* d_out, int out_size, void* d_ws, size_t ws_size,
                              hipStream_t stream)
{
    (void)in_sizes; (void)n_in; (void)out_size; (void)ws_size;
    const float* x       = (const float*)d_in[0];
    const float* u_noise = (const float*)d_in[1];
    const float* W_enc   = (const float*)d_in[2];
    const float* b_enc   = (const float*)d_in[3];
    const float* start_e = (const float*)d_in[4];
    const float* W_tok   = (const float*)d_in[5];
    const float* b_tok   = (const float*)d_in[6];
    const float* Wz      = (const float*)d_in[7];
    const float* bz      = (const float*)d_in[8];
    const float* Wr      = (const float*)d_in[9];
    const float* br      = (const float*)d_in[10];
    const float* Wh      = (const float*)d_in[11];
    const float* bh      = (const float*)d_in[12];
    const float* W_out   = (const float*)d_in[13];
    const float* b_out   = (const float*)d_in[14];

    float* out = (float*)d_out;
    float* out_msg = out;                                   // (B, T*V)
    float* out_logits = out + (size_t)B_ * T_ * V_;         // (T, B, V)
    float* out_nt = out_logits + (size_t)T_ * B_ * V_;      // (B,)

    // ---- workspace layout (~148.1 MB) ----
    char* wsb = (char*)d_ws;
    const size_t MB = 1024 * 1024;
    unsigned short* wzb_hi = (unsigned short*)(wsb + 0 * MB);    // 2MB each
    unsigned short* wzb_lo = (unsigned short*)(wsb + 2 * MB);
    unsigned short* wrb_hi = (unsigned short*)(wsb + 4 * MB);
    unsigned short* wrb_lo = (unsigned short*)(wsb + 6 * MB);
    unsigned short* whb_hi = (unsigned short*)(wsb + 8 * MB);
    unsigned short* whb_lo = (unsigned short*)(wsb + 10 * MB);
    unsigned short* we_hi  = (unsigned short*)(wsb + 12 * MB);   // 4MB
    unsigned short* we_lo  = (unsigned short*)(wsb + 16 * MB);   // 4MB
    unsigned short* x_hi   = (unsigned short*)(wsb + 20 * MB);   // 32MB
    unsigned short* x_lo   = (unsigned short*)(wsb + 52 * MB);   // 32MB
    float*  zbuf  = (float*)(wsb + 20 * MB);                     // alias x_hi
    unsigned short* rh_hi  = (unsigned short*)(wsb + 52 * MB);   // alias x_lo
    unsigned short* rh_lo  = (unsigned short*)(wsb + 68 * MB);
    float*  hbuf  = (float*)(wsb + 84 * MB);                     // 32MB
    unsigned short* h_hi   = (unsigned short*)(wsb + 116 * MB);  // 16MB
    unsigned short* h_lo   = (unsigned short*)(wsb + 132 * MB);  // 16MB
    float* Pz = (float*)(wsb + 148 * MB);                        // 7x1024 each
    float* Pr = Pz + 7 * 1024;
    float* Ph = Pr + 7 * 1024;
    int* tokidx = (int*)(Ph + 7 * 1024);
    float* rcb = (float*)(tokidx + B_);
    float* ntb = rcb + B_;

    // ---- one-time conversions / tables ----
    conv_wb<<<512, 256, 0, stream>>>(Wz, wzb_hi, wzb_lo);
    conv_wb<<<512, 256, 0, stream>>>(Wr, wrb_hi, wrb_lo);
    conv_wb<<<512, 256, 0, stream>>>(Wh, whb_hi, whb_lo);
    conv_w<<<1024, 256, 0, stream>>>(W_enc, we_hi, we_lo);
    conv_x<<<8192, 256, 0, stream>>>(x, x_hi, x_lo);
    prep_tables<<<dim3(4, 3), 256, 0, stream>>>(Wz, Wr, Wh, bz, br, bh,
                                                W_tok, b_tok, start_e, Pz, Pr, Ph);
    init_misc<<<32, 256, 0, stream>>>(tokidx, rcb, ntb);

    // ---- encoder: h0 = x @ W_enc + b_enc (K=2048) ----
    gemm_bt<<<dim3(8, 64), 512, 0, stream>>>(
        x_hi, x_lo, we_hi, we_lo, nullptr, nullptr,
        b_enc, nullptr, nullptr,
        nullptr, hbuf, nullptr, h_hi, h_lo, 256, 0);

    for (int t = 0; t < T_; ++t) {
        // z = sigmoid(h@Wz_bot + Pz[tok]); rh = sigmoid(h@Wr_bot + Pr[tok]) * h
        gemm_bt<<<dim3(16, 64), 512, 0, stream>>>(
            h_hi, h_lo, wzb_hi, wzb_lo, wrb_hi, wrb_lo,
            Pz, Pr, tokidx,
            nullptr, hbuf, zbuf, rh_hi, rh_lo, 128, 1);
        // h = (1-z)h + z*tanh(rh@Wh_bot + Ph[tok])
        gemm_bt<<<dim3(8, 64), 512, 0, stream>>>(
            rh_hi, rh_lo, whb_hi, whb_lo, nullptr, nullptr,
            Ph, nullptr, tokidx,
            zbuf, hbuf, nullptr, h_hi, h_lo, 128, 2);
        // logits / gumbel argmax / outputs / tokidx
        step_tok<<<B_ / 4, 256, 0, stream>>>(
            hbuf, W_out, b_out, u_noise + (size_t)t * B_ * V_,
            rcb, ntb, tokidx, out_msg,
            out_logits + (size_t)t * B_ * V_, out_nt, t);
    }
}